// Round 1
// baseline (722.220 us; speedup 1.0000x reference)
//
#include <hip/hip_runtime.h>

typedef float f32x4 __attribute__((ext_vector_type(4)));
typedef short s16x8 __attribute__((ext_vector_type(8)));

#define B_ 32
#define C_ 256
#define H_ 56
#define W_ 56
#define R_ 64
#define HW_ (H_*W_)     // 3136
#define CH_ 14336       // C_*H_ == C_*W_
#define RPB 2           // h-rows per block in main kernel
#define CP 68           // padded r-stride (bank-conflict-free f32x4 reads)
#define SGP 58          // padded w-stride for logit tile

// ---------- helpers ----------
__device__ __forceinline__ unsigned short f2bf(float f) {
    unsigned u = __float_as_uint(f);
    u += 0x7fffu + ((u >> 16) & 1u);     // round-to-nearest-even
    return (unsigned short)(u >> 16);
}

__device__ __forceinline__ s16x8 pack8(f32x4 a, f32x4 b) {
    s16x8 r;
    r[0] = (short)f2bf(a[0]); r[1] = (short)f2bf(a[1]);
    r[2] = (short)f2bf(a[2]); r[3] = (short)f2bf(a[3]);
    r[4] = (short)f2bf(b[0]); r[5] = (short)f2bf(b[1]);
    r[6] = (short)f2bf(b[2]); r[7] = (short)f2bf(b[3]);
    return r;
}

// ---------- K1: GAP reductions ----------
// one block per (b,c) plane; produces gapc (mean over HW) directly and
// atomically accumulates raw sums into gw[b][w] (sum over c,h) and gh[b][h].
__global__ __launch_bounds__(256) void k_reduce(const float* __restrict__ x,
                                                float* __restrict__ gapc,
                                                float* __restrict__ gw,
                                                float* __restrict__ gh) {
    const int b = blockIdx.x >> 8;
    const int c = blockIdx.x & 255;
    const float* px = x + (size_t)(b * C_ + c) * HW_;
    __shared__ float sp[HW_];
    __shared__ float spart[4];
    const int tid = threadIdx.x;
    float tot = 0.f;
    for (int j = tid; j < HW_ / 4; j += 256) {
        f32x4 v = *(const f32x4*)(px + j * 4);
        *(f32x4*)&sp[j * 4] = v;
        tot += v[0] + v[1] + v[2] + v[3];
    }
    for (int d = 32; d > 0; d >>= 1) tot += __shfl_xor(tot, d, 64);
    const int lane = tid & 63, wid = tid >> 6;
    if (lane == 0) spart[wid] = tot;
    __syncthreads();
    if (tid == 0)
        gapc[b * C_ + c] = (spart[0] + spart[1] + spart[2] + spart[3]) * (1.f / HW_);
    if (tid < W_) {
        float s = 0.f;
        for (int h = 0; h < H_; ++h) s += sp[h * W_ + tid];
        atomicAdd(&gw[b * W_ + tid], s);
    } else if (tid >= 64 && tid < 64 + H_) {
        const int h = tid - 64;
        float s = 0.f;
        for (int w = 0; w < W_; ++w) s += sp[h * W_ + w];
        atomicAdd(&gh[b * H_ + h], s);
    }
}

// ---------- K3: fused CP-reconstruct + softmax + conv3d gate ----------
__global__ __launch_bounds__(1024) void k_main(
    const float* __restrict__ x,
    const float* __restrict__ Wc, const float* __restrict__ acp,
    const float* __restrict__ Ww, const float* __restrict__ awp,
    const float* __restrict__ Wh, const float* __restrict__ ahp,
    const float* __restrict__ W3,
    const float* __restrict__ gapc, const float* __restrict__ gw,
    const float* __restrict__ gh,
    float* __restrict__ out)
{
    __shared__ float scout[C_ * CP];          // c_out[b][c][r]          69632 B
    __shared__ float swout[64 * CP];          // w_out[b][w][r] (w>=56 zero) 17408 B
    __shared__ float shout[RPB * CP];         // h_out[b][h0+hr][r]        544 B
    __shared__ float sg[C_ * SGP + 16];       // logits s[c][w]          59456 B
    __shared__ float sredA[16 * 64];          //                          4096 B
    __shared__ float sredB[16 * 64];          //                          4096 B

    const int b   = blockIdx.x;
    const int h0  = blockIdx.y * RPB;
    const int tid = threadIdx.x;
    const int lane = tid & 63;
    const int wid  = tid >> 6;
    const int g    = lane >> 4;
    const int col  = lane & 15;
    const float ac = acp[0], aw = awp[0], ah = ahp[0];

    // ----- staging: build factor matrices straight from the GAP results -----
    const float* gc = gapc + b * C_;
    for (int idx = tid; idx < C_ * R_; idx += 1024) {
        const int c = idx >> 6, r = idx & 63;
        const float gm = (c >= 1)      ? gc[c - 1] : 0.f;
        const float g0 = gc[c];
        const float gp = (c < C_ - 1)  ? gc[c + 1] : 0.f;
        float v = Wc[r * 3 + 0] * gm + Wc[r * 3 + 1] * g0 + Wc[r * 3 + 2] * gp;
        scout[c * CP + r] = (v >= 0.f) ? v : ac * v;
    }
    const float* gwb = gw + b * W_;
    for (int idx = tid; idx < 64 * R_; idx += 1024) {
        const int w = idx >> 6, r = idx & 63;
        float v = 0.f;
        if (w < W_) {
            const float gm = (w >= 1)     ? gwb[w - 1] * (1.f / CH_) : 0.f;
            const float g0 = gwb[w] * (1.f / CH_);
            const float gp = (w < W_ - 1) ? gwb[w + 1] * (1.f / CH_) : 0.f;
            v = Ww[r * 3 + 0] * gm + Ww[r * 3 + 1] * g0 + Ww[r * 3 + 2] * gp;
            v = (v >= 0.f) ? v : aw * v;
        }
        swout[w * CP + r] = v;
    }
    const float* ghb = gh + b * H_;
    if (tid < RPB * R_) {
        const int hr = tid >> 6, r = tid & 63;
        const int h = h0 + hr;
        const float gm = (h >= 1)     ? ghb[h - 1] * (1.f / CH_) : 0.f;
        const float g0 = ghb[h] * (1.f / CH_);
        const float gp = (h < H_ - 1) ? ghb[h + 1] * (1.f / CH_) : 0.f;
        float v = Wh[r * 3 + 0] * gm + Wh[r * 3 + 1] * g0 + Wh[r * 3 + 2] * gp;
        shout[hr * CP + r] = (v >= 0.f) ? v : ah * v;
    }
    __syncthreads();

    // ----- B fragments (w_out), static across both rows -----
    s16x8 bfrag[4][2];
    #pragma unroll
    for (int t = 0; t < 4; ++t)
        #pragma unroll
        for (int kc = 0; kc < 2; ++kc) {
            const int r0 = kc * 32 + g * 4;
            const int w  = t * 16 + col;
            f32x4 fa = *(f32x4*)&swout[w * CP + r0];
            f32x4 fb = *(f32x4*)&swout[w * CP + r0 + 16];
            bfrag[t][kc] = pack8(fa, fb);
        }

    const int cbase = wid * 16;

    for (int hr = 0; hr < RPB; ++hr) {
        const int h = h0 + hr;
        // ----- MFMA: s = (c_out * h_out) x w_out -----
        f32x4 acc0 = {0,0,0,0}, acc1 = {0,0,0,0}, acc2 = {0,0,0,0}, acc3 = {0,0,0,0};
        const int crow = cbase + col;     // A-operand row lives on lane&15
        #pragma unroll
        for (int kc = 0; kc < 2; ++kc) {
            const int r0 = kc * 32 + g * 4;
            f32x4 ca = *(f32x4*)&scout[crow * CP + r0];
            f32x4 cb = *(f32x4*)&scout[crow * CP + r0 + 16];
            f32x4 ha = *(f32x4*)&shout[hr * CP + r0];
            f32x4 hb = *(f32x4*)&shout[hr * CP + r0 + 16];
            s16x8 afrag = pack8(ca * ha, cb * hb);
            acc0 = __builtin_amdgcn_mfma_f32_16x16x32_bf16(afrag, bfrag[0][kc], acc0, 0, 0, 0);
            acc1 = __builtin_amdgcn_mfma_f32_16x16x32_bf16(afrag, bfrag[1][kc], acc1, 0, 0, 0);
            acc2 = __builtin_amdgcn_mfma_f32_16x16x32_bf16(afrag, bfrag[2][kc], acc2, 0, 0, 0);
            acc3 = __builtin_amdgcn_mfma_f32_16x16x32_bf16(afrag, bfrag[3][kc], acc3, 0, 0, 0);
        }
        // ----- write logits to LDS (D layout: row=4*(lane>>4)+reg, col=lane&15) -----
        {
            const int cr = cbase + g * 4;
            #pragma unroll
            for (int t = 0; t < 4; ++t) {
                const int w = t * 16 + col;
                if (w < W_) {
                    f32x4 a = (t == 0) ? acc0 : (t == 1) ? acc1 : (t == 2) ? acc2 : acc3;
                    sg[(cr + 0) * SGP + w] = a[0];
                    sg[(cr + 1) * SGP + w] = a[1];
                    sg[(cr + 2) * SGP + w] = a[2];
                    sg[(cr + 3) * SGP + w] = a[3];
                }
            }
        }
        __syncthreads();

        // ----- remapped phase: lane = w, wave = 16-channel chunk -----
        float p[16];
        #pragma unroll
        for (int k = 0; k < 16; ++k) p[k] = sg[(cbase + k) * SGP + lane];
        float m16 = p[0];
        #pragma unroll
        for (int k = 1; k < 16; ++k) m16 = fmaxf(m16, p[k]);
        sredA[wid * 64 + lane] = m16;
        __syncthreads();
        float M = sredA[lane];
        #pragma unroll
        for (int t = 1; t < 16; ++t) M = fmaxf(M, sredA[t * 64 + lane]);
        float S = 0.f;
        #pragma unroll
        for (int k = 0; k < 16; ++k) { p[k] = __expf(p[k] - M); S += p[k]; }
        sredB[wid * 64 + lane] = S;
        __syncthreads();
        S = 0.f;
        #pragma unroll
        for (int t = 0; t < 16; ++t) S += sredB[t * 64 + lane];
        const float invS = 1.f / S;

        // ----- conv3d (3x3x3, zero-pad) via row loads + DPP lane shifts -----
        float res[16];
        #pragma unroll
        for (int k = 0; k < 16; ++k) res[k] = 0.f;
        const float* xb = x + (size_t)b * C_ * HW_;
        #pragma unroll
        for (int ci = 0; ci < 18; ++ci) {
            const int cc = cbase - 1 + ci;
            const bool cok = (cc >= 0) && (cc < C_);
            #pragma unroll
            for (int jh = 0; jh < 3; ++jh) {
                const int hh = h - 1 + jh;
                const bool hok = (hh >= 0) && (hh < H_);
                float v = 0.f;
                if (cok && hok && lane < W_) v = xb[(cc * H_ + hh) * W_ + lane];
                float vl = __int_as_float(__builtin_amdgcn_mov_dpp(__float_as_int(v), 0x138, 0xf, 0xf, true)); // wave_shr:1 -> value at w-1
                float vr = __int_as_float(__builtin_amdgcn_mov_dpp(__float_as_int(v), 0x130, 0xf, 0xf, true)); // wave_shl:1 -> value at w+1
                vl = (lane == 0) ? 0.f : vl;
                if (ci >= 2) { const int k = ci - 2;
                    res[k] += W3[(2*3+jh)*3+0]*vl + W3[(2*3+jh)*3+1]*v + W3[(2*3+jh)*3+2]*vr; }
                if (ci >= 1 && ci <= 16) { const int k = ci - 1;
                    res[k] += W3[(1*3+jh)*3+0]*vl + W3[(1*3+jh)*3+1]*v + W3[(1*3+jh)*3+2]*vr; }
                if (ci <= 15) { const int k = ci;
                    res[k] += W3[(0*3+jh)*3+0]*vl + W3[(0*3+jh)*3+1]*v + W3[(0*3+jh)*3+2]*vr; }
            }
        }
        // ----- gated residual store -----
        if (lane < W_) {
            #pragma unroll
            for (int k = 0; k < 16; ++k) {
                const size_t idx = ((size_t)(b * C_ + cbase + k) * H_ + h) * W_ + lane;
                const float xm = x[idx];
                out[idx] = res[k] * (p[k] * invS) + xm;
            }
        }
        __syncthreads();   // protect sg/sred reuse next row
    }
}

extern "C" void kernel_launch(void* const* d_in, const int* in_sizes, int n_in,
                              void* d_out, int out_size, void* d_ws, size_t ws_size,
                              hipStream_t stream) {
    const float* x  = (const float*)d_in[0];
    const float* Wc = (const float*)d_in[1];
    const float* ac = (const float*)d_in[2];
    const float* Ww = (const float*)d_in[3];
    const float* aw = (const float*)d_in[4];
    const float* Wh = (const float*)d_in[5];
    const float* ah = (const float*)d_in[6];
    const float* W3 = (const float*)d_in[7];
    float* out  = (float*)d_out;
    float* gapc = (float*)d_ws;                 // B*C
    float* gwp  = gapc + B_ * C_;               // B*W (raw sums)
    float* ghp  = gwp + B_ * W_;                // B*H (raw sums)

    hipMemsetAsync(gwp, 0, (size_t)(B_ * W_ + B_ * H_) * sizeof(float), stream);
    k_reduce<<<dim3(B_ * C_), dim3(256), 0, stream>>>(x, gapc, gwp, ghp);
    k_main<<<dim3(B_, H_ / RPB), dim3(1024), 0, stream>>>(
        x, Wc, ac, Ww, aw, Wh, ah, W3, gapc, gwp, ghp, out);
}

// Round 2
// 711.242 us; speedup vs baseline: 1.0154x; 1.0154x over previous
//
#include <hip/hip_runtime.h>

typedef float f32x4 __attribute__((ext_vector_type(4)));
typedef short s16x8 __attribute__((ext_vector_type(8)));

#define B_ 32
#define C_ 256
#define H_ 56
#define W_ 56
#define R_ 64
#define HW_ (H_*W_)     // 3136
#define CH_ 14336       // C_*H_ == C_*W_
#define RPB 2           // h-rows per block in main kernel
#define CP 68           // padded r-stride (bank-conflict-free f32x4 reads)
#define SGP 58          // padded w-stride for logit tile

// ---------- helpers ----------
__device__ __forceinline__ unsigned short f2bf(float f) {
    unsigned u = __float_as_uint(f);
    u += 0x7fffu + ((u >> 16) & 1u);     // round-to-nearest-even
    return (unsigned short)(u >> 16);
}

__device__ __forceinline__ s16x8 pack8(f32x4 a, f32x4 b) {
    s16x8 r;
    r[0] = (short)f2bf(a[0]); r[1] = (short)f2bf(a[1]);
    r[2] = (short)f2bf(a[2]); r[3] = (short)f2bf(a[3]);
    r[4] = (short)f2bf(b[0]); r[5] = (short)f2bf(b[1]);
    r[6] = (short)f2bf(b[2]); r[7] = (short)f2bf(b[3]);
    return r;
}

// ---------- K1: GAP reductions ----------
__global__ __launch_bounds__(256) void k_reduce(const float* __restrict__ x,
                                                float* __restrict__ gapc,
                                                float* __restrict__ gw,
                                                float* __restrict__ gh) {
    const int b = blockIdx.x >> 8;
    const int c = blockIdx.x & 255;
    const float* px = x + (size_t)(b * C_ + c) * HW_;
    __shared__ float sp[HW_];
    __shared__ float spart[4];
    const int tid = threadIdx.x;
    float tot = 0.f;
    for (int j = tid; j < HW_ / 4; j += 256) {
        f32x4 v = *(const f32x4*)(px + j * 4);
        *(f32x4*)&sp[j * 4] = v;
        tot += v[0] + v[1] + v[2] + v[3];
    }
    for (int d = 32; d > 0; d >>= 1) tot += __shfl_xor(tot, d, 64);
    const int lane = tid & 63, wid = tid >> 6;
    if (lane == 0) spart[wid] = tot;
    __syncthreads();
    if (tid == 0)
        gapc[b * C_ + c] = (spart[0] + spart[1] + spart[2] + spart[3]) * (1.f / HW_);
    if (tid < W_) {
        float s = 0.f;
        for (int h = 0; h < H_; ++h) s += sp[h * W_ + tid];
        atomicAdd(&gw[b * W_ + tid], s);
    } else if (tid >= 64 && tid < 64 + H_) {
        const int h = tid - 64;
        float s = 0.f;
        for (int w = 0; w < W_; ++w) s += sp[h * W_ + w];
        atomicAdd(&gh[b * H_ + h], s);
    }
}

// ---------- K3: fused CP-reconstruct + softmax + conv3d gate ----------
// 1024 threads = 16 waves = 4 waves/SIMD -> VGPR budget 512/4 = 128. Declare it.
__global__ __launch_bounds__(1024, 4) void k_main(
    const float* __restrict__ x,
    const float* __restrict__ Wc, const float* __restrict__ acp,
    const float* __restrict__ Ww, const float* __restrict__ awp,
    const float* __restrict__ Wh, const float* __restrict__ ahp,
    const float* __restrict__ W3,
    const float* __restrict__ gapc, const float* __restrict__ gw,
    const float* __restrict__ gh,
    float* __restrict__ out)
{
    __shared__ float scout[C_ * CP];          // c_out[b][c][r]          69632 B
    __shared__ float swout[64 * CP];          // w_out[b][w][r]          17408 B
    __shared__ float shout[RPB * CP];         // h_out[b][h0+hr][r]        544 B
    __shared__ float sg[C_ * SGP + 16];       // logits s[c][w]          59456 B
    __shared__ float sredA[16 * 64];          //                          4096 B
    __shared__ float sredB[16 * 64];          //                          4096 B

    const int b   = blockIdx.x;
    const int h0  = blockIdx.y * RPB;
    const int tid = threadIdx.x;
    const int lane = tid & 63;
    const int wid  = tid >> 6;
    const int g    = lane >> 4;
    const int col  = lane & 15;
    const float ac = acp[0], aw = awp[0], ah = ahp[0];

    // ----- staging: build factor matrices straight from the GAP results -----
    const float* gc = gapc + b * C_;
    for (int idx = tid; idx < C_ * R_; idx += 1024) {
        const int c = idx >> 6, r = idx & 63;
        const float gm = (c >= 1)      ? gc[c - 1] : 0.f;
        const float g0 = gc[c];
        const float gp = (c < C_ - 1)  ? gc[c + 1] : 0.f;
        float v = Wc[r * 3 + 0] * gm + Wc[r * 3 + 1] * g0 + Wc[r * 3 + 2] * gp;
        scout[c * CP + r] = (v >= 0.f) ? v : ac * v;
    }
    const float* gwb = gw + b * W_;
    for (int idx = tid; idx < 64 * R_; idx += 1024) {
        const int w = idx >> 6, r = idx & 63;
        float v = 0.f;
        if (w < W_) {
            const float gm = (w >= 1)     ? gwb[w - 1] * (1.f / CH_) : 0.f;
            const float g0 = gwb[w] * (1.f / CH_);
            const float gp = (w < W_ - 1) ? gwb[w + 1] * (1.f / CH_) : 0.f;
            v = Ww[r * 3 + 0] * gm + Ww[r * 3 + 1] * g0 + Ww[r * 3 + 2] * gp;
            v = (v >= 0.f) ? v : aw * v;
        }
        swout[w * CP + r] = v;
    }
    const float* ghb = gh + b * H_;
    if (tid < RPB * R_) {
        const int hr = tid >> 6, r = tid & 63;
        const int h = h0 + hr;
        const float gm = (h >= 1)     ? ghb[h - 1] * (1.f / CH_) : 0.f;
        const float g0 = ghb[h] * (1.f / CH_);
        const float gp = (h < H_ - 1) ? ghb[h + 1] * (1.f / CH_) : 0.f;
        float v = Wh[r * 3 + 0] * gm + Wh[r * 3 + 1] * g0 + Wh[r * 3 + 2] * gp;
        shout[hr * CP + r] = (v >= 0.f) ? v : ah * v;
    }
    __syncthreads();

    // ----- B fragments (w_out), static across both rows -----
    s16x8 bfrag[4][2];
    #pragma unroll
    for (int t = 0; t < 4; ++t)
        #pragma unroll
        for (int kc = 0; kc < 2; ++kc) {
            const int r0 = kc * 32 + g * 4;
            const int w  = t * 16 + col;
            f32x4 fa = *(f32x4*)&swout[w * CP + r0];
            f32x4 fb = *(f32x4*)&swout[w * CP + r0 + 16];
            bfrag[t][kc] = pack8(fa, fb);
        }

    const int cbase = wid * 16;

    for (int hr = 0; hr < RPB; ++hr) {
        const int h = h0 + hr;
        // ----- MFMA: s = (c_out * h_out) x w_out -----
        f32x4 acc0 = {0,0,0,0}, acc1 = {0,0,0,0}, acc2 = {0,0,0,0}, acc3 = {0,0,0,0};
        const int crow = cbase + col;     // A-operand row lives on lane&15
        #pragma unroll
        for (int kc = 0; kc < 2; ++kc) {
            const int r0 = kc * 32 + g * 4;
            f32x4 ca = *(f32x4*)&scout[crow * CP + r0];
            f32x4 cb = *(f32x4*)&scout[crow * CP + r0 + 16];
            f32x4 ha = *(f32x4*)&shout[hr * CP + r0];
            f32x4 hb = *(f32x4*)&shout[hr * CP + r0 + 16];
            s16x8 afrag = pack8(ca * ha, cb * hb);
            acc0 = __builtin_amdgcn_mfma_f32_16x16x32_bf16(afrag, bfrag[0][kc], acc0, 0, 0, 0);
            acc1 = __builtin_amdgcn_mfma_f32_16x16x32_bf16(afrag, bfrag[1][kc], acc1, 0, 0, 0);
            acc2 = __builtin_amdgcn_mfma_f32_16x16x32_bf16(afrag, bfrag[2][kc], acc2, 0, 0, 0);
            acc3 = __builtin_amdgcn_mfma_f32_16x16x32_bf16(afrag, bfrag[3][kc], acc3, 0, 0, 0);
        }
        // ----- write logits to LDS (D layout: row=4*(lane>>4)+reg, col=lane&15) -----
        {
            const int cr = cbase + g * 4;
            #pragma unroll
            for (int t = 0; t < 4; ++t) {
                const int w = t * 16 + col;
                if (w < W_) {
                    f32x4 a = (t == 0) ? acc0 : (t == 1) ? acc1 : (t == 2) ? acc2 : acc3;
                    sg[(cr + 0) * SGP + w] = a[0];
                    sg[(cr + 1) * SGP + w] = a[1];
                    sg[(cr + 2) * SGP + w] = a[2];
                    sg[(cr + 3) * SGP + w] = a[3];
                }
            }
        }
        __syncthreads();

        // ----- remapped phase: lane = w, wave = 16-channel chunk -----
        float p[16];
        #pragma unroll
        for (int k = 0; k < 16; ++k) p[k] = sg[(cbase + k) * SGP + lane];
        float m16 = p[0];
        #pragma unroll
        for (int k = 1; k < 16; ++k) m16 = fmaxf(m16, p[k]);
        sredA[wid * 64 + lane] = m16;
        __syncthreads();
        float M = sredA[lane];
        #pragma unroll
        for (int t = 1; t < 16; ++t) M = fmaxf(M, sredA[t * 64 + lane]);
        float S = 0.f;
        #pragma unroll
        for (int k = 0; k < 16; ++k) { p[k] = __expf(p[k] - M); S += p[k]; }
        sredB[wid * 64 + lane] = S;
        __syncthreads();
        S = 0.f;
        #pragma unroll
        for (int t = 0; t < 16; ++t) S += sredB[t * 64 + lane];
        const float invS = 1.f / S;

        // ----- conv3d (3x3x3, zero-pad) via row loads + DPP lane shifts -----
        float res[16];
        float xm[16];
        #pragma unroll
        for (int k = 0; k < 16; ++k) res[k] = 0.f;
        const float* xb = x + (size_t)b * C_ * HW_;
        #pragma unroll
        for (int ci = 0; ci < 18; ++ci) {
            const int cc = cbase - 1 + ci;
            const bool cok = (cc >= 0) && (cc < C_);
            #pragma unroll
            for (int jh = 0; jh < 3; ++jh) {
                const int hh = h - 1 + jh;
                const bool hok = (hh >= 0) && (hh < H_);
                float v = 0.f;
                if (cok && hok && lane < W_) v = xb[(cc * H_ + hh) * W_ + lane];
                float vl = __int_as_float(__builtin_amdgcn_mov_dpp(__float_as_int(v), 0x138, 0xf, 0xf, true)); // wave_shr:1 -> value at w-1
                float vr = __int_as_float(__builtin_amdgcn_mov_dpp(__float_as_int(v), 0x130, 0xf, 0xf, true)); // wave_shl:1 -> value at w+1
                vl = (lane == 0) ? 0.f : vl;
                if (ci >= 1 && ci <= 16 && jh == 1) xm[ci - 1] = v;  // residual x, reused at store
                if (ci >= 2) { const int k = ci - 2;
                    res[k] += W3[(2*3+jh)*3+0]*vl + W3[(2*3+jh)*3+1]*v + W3[(2*3+jh)*3+2]*vr; }
                if (ci >= 1 && ci <= 16) { const int k = ci - 1;
                    res[k] += W3[(1*3+jh)*3+0]*vl + W3[(1*3+jh)*3+1]*v + W3[(1*3+jh)*3+2]*vr; }
                if (ci <= 15) { const int k = ci;
                    res[k] += W3[(0*3+jh)*3+0]*vl + W3[(0*3+jh)*3+1]*v + W3[(0*3+jh)*3+2]*vr; }
            }
        }
        // ----- gated residual store -----
        if (lane < W_) {
            #pragma unroll
            for (int k = 0; k < 16; ++k) {
                const size_t idx = ((size_t)(b * C_ + cbase + k) * H_ + h) * W_ + lane;
                out[idx] = res[k] * (p[k] * invS) + xm[k];
            }
        }
        __syncthreads();   // protect sg/sred reuse next row
    }
}

extern "C" void kernel_launch(void* const* d_in, const int* in_sizes, int n_in,
                              void* d_out, int out_size, void* d_ws, size_t ws_size,
                              hipStream_t stream) {
    const float* x  = (const float*)d_in[0];
    const float* Wc = (const float*)d_in[1];
    const float* ac = (const float*)d_in[2];
    const float* Ww = (const float*)d_in[3];
    const float* aw = (const float*)d_in[4];
    const float* Wh = (const float*)d_in[5];
    const float* ah = (const float*)d_in[6];
    const float* W3 = (const float*)d_in[7];
    float* out  = (float*)d_out;
    float* gapc = (float*)d_ws;                 // B*C
    float* gwp  = gapc + B_ * C_;               // B*W (raw sums)
    float* ghp  = gwp + B_ * W_;                // B*H (raw sums)

    hipMemsetAsync(gwp, 0, (size_t)(B_ * W_ + B_ * H_) * sizeof(float), stream);
    k_reduce<<<dim3(B_ * C_), dim3(256), 0, stream>>>(x, gapc, gwp, ghp);
    k_main<<<dim3(B_, H_ / RPB), dim3(1024), 0, stream>>>(
        x, Wc, ac, Ww, aw, Wh, ah, W3, gapc, gwp, ghp, out);
}

// Round 3
// 390.682 us; speedup vs baseline: 1.8486x; 1.8205x over previous
//
#include <hip/hip_runtime.h>

typedef float f32x4 __attribute__((ext_vector_type(4)));
typedef short s16x8 __attribute__((ext_vector_type(8)));

#define B_ 32
#define C_ 256
#define H_ 56
#define W_ 56
#define R_ 64
#define HW_ (H_*W_)     // 3136
#define CH_ 14336       // C_*H_ == C_*W_
#define RPB 2           // h-rows per block in main kernel
#define CP 68           // padded r-stride (bank-conflict-free f32x4 reads)
#define SGP 58          // padded w-stride for logit tile

// ---------- helpers ----------
__device__ __forceinline__ unsigned short f2bf(float f) {
    unsigned u = __float_as_uint(f);
    u += 0x7fffu + ((u >> 16) & 1u);     // round-to-nearest-even
    return (unsigned short)(u >> 16);
}

__device__ __forceinline__ s16x8 pack8(f32x4 a, f32x4 b) {
    s16x8 r;
    r[0] = (short)f2bf(a[0]); r[1] = (short)f2bf(a[1]);
    r[2] = (short)f2bf(a[2]); r[3] = (short)f2bf(a[3]);
    r[4] = (short)f2bf(b[0]); r[5] = (short)f2bf(b[1]);
    r[6] = (short)f2bf(b[2]); r[7] = (short)f2bf(b[3]);
    return r;
}

// ---------- K1: GAP reductions ----------
__global__ __launch_bounds__(256) void k_reduce(const float* __restrict__ x,
                                                float* __restrict__ gapc,
                                                float* __restrict__ gw,
                                                float* __restrict__ gh) {
    const int b = blockIdx.x >> 8;
    const int c = blockIdx.x & 255;
    const float* px = x + (size_t)(b * C_ + c) * HW_;
    __shared__ float sp[HW_];
    __shared__ float spart[4];
    const int tid = threadIdx.x;
    float tot = 0.f;
    for (int j = tid; j < HW_ / 4; j += 256) {
        f32x4 v = *(const f32x4*)(px + j * 4);
        *(f32x4*)&sp[j * 4] = v;
        tot += v[0] + v[1] + v[2] + v[3];
    }
    for (int d = 32; d > 0; d >>= 1) tot += __shfl_xor(tot, d, 64);
    const int lane = tid & 63, wid = tid >> 6;
    if (lane == 0) spart[wid] = tot;
    __syncthreads();
    if (tid == 0)
        gapc[b * C_ + c] = (spart[0] + spart[1] + spart[2] + spart[3]) * (1.f / HW_);
    if (tid < W_) {
        float s = 0.f;
        for (int h = 0; h < H_; ++h) s += sp[h * W_ + tid];
        atomicAdd(&gw[b * W_ + tid], s);
    } else if (tid >= 64 && tid < 64 + H_) {
        const int h = tid - 64;
        float s = 0.f;
        for (int w = 0; w < W_; ++w) s += sp[h * W_ + w];
        atomicAdd(&gh[b * H_ + h], s);
    }
}

// ---------- K3: fused CP-reconstruct + softmax + conv3d gate ----------
// Register-pressure-disciplined: gate lives in LDS (overwritten into sg),
// conv processed in 2 chunks of 8 channels so peak live regs < 64.
__global__ __launch_bounds__(1024)
__attribute__((amdgpu_waves_per_eu(4, 4)))
void k_main(
    const float* __restrict__ x,
    const float* __restrict__ Wc, const float* __restrict__ acp,
    const float* __restrict__ Ww, const float* __restrict__ awp,
    const float* __restrict__ Wh, const float* __restrict__ ahp,
    const float* __restrict__ W3,
    const float* __restrict__ gapc, const float* __restrict__ gw,
    const float* __restrict__ gh,
    float* __restrict__ out)
{
    __shared__ float scout[C_ * CP];          // c_out[b][c][r]          69632 B
    __shared__ float swout[64 * CP];          // w_out[b][w][r]          17408 B
    __shared__ float shout[RPB * CP];         // h_out[b][h0+hr][r]        544 B
    __shared__ float sg[C_ * SGP + 16];       // logits -> gates         59456 B
    __shared__ float sredA[16 * 64];          //                          4096 B
    __shared__ float sredB[16 * 64];          //                          4096 B

    const int b   = blockIdx.x;
    const int h0  = blockIdx.y * RPB;
    const int tid = threadIdx.x;
    const int lane = tid & 63;
    const int wid  = tid >> 6;
    const int g    = lane >> 4;
    const int col  = lane & 15;
    const float ac = acp[0], aw = awp[0], ah = ahp[0];

    // ----- staging: build factor matrices straight from the GAP results -----
    const float* gc = gapc + b * C_;
    for (int idx = tid; idx < C_ * R_; idx += 1024) {
        const int c = idx >> 6, r = idx & 63;
        const float gm = (c >= 1)      ? gc[c - 1] : 0.f;
        const float g0 = gc[c];
        const float gp = (c < C_ - 1)  ? gc[c + 1] : 0.f;
        float v = Wc[r * 3 + 0] * gm + Wc[r * 3 + 1] * g0 + Wc[r * 3 + 2] * gp;
        scout[c * CP + r] = (v >= 0.f) ? v : ac * v;
    }
    const float* gwb = gw + b * W_;
    for (int idx = tid; idx < 64 * R_; idx += 1024) {
        const int w = idx >> 6, r = idx & 63;
        float v = 0.f;
        if (w < W_) {
            const float gm = (w >= 1)     ? gwb[w - 1] * (1.f / CH_) : 0.f;
            const float g0 = gwb[w] * (1.f / CH_);
            const float gp = (w < W_ - 1) ? gwb[w + 1] * (1.f / CH_) : 0.f;
            v = Ww[r * 3 + 0] * gm + Ww[r * 3 + 1] * g0 + Ww[r * 3 + 2] * gp;
            v = (v >= 0.f) ? v : aw * v;
        }
        swout[w * CP + r] = v;
    }
    const float* ghb = gh + b * H_;
    if (tid < RPB * R_) {
        const int hr = tid >> 6, r = tid & 63;
        const int h = h0 + hr;
        const float gm = (h >= 1)     ? ghb[h - 1] * (1.f / CH_) : 0.f;
        const float g0 = ghb[h] * (1.f / CH_);
        const float gp = (h < H_ - 1) ? ghb[h + 1] * (1.f / CH_) : 0.f;
        float v = Wh[r * 3 + 0] * gm + Wh[r * 3 + 1] * g0 + Wh[r * 3 + 2] * gp;
        shout[hr * CP + r] = (v >= 0.f) ? v : ah * v;
    }
    __syncthreads();

    // ----- B fragments (w_out), static across both rows -----
    s16x8 bfrag[4][2];
    #pragma unroll
    for (int t = 0; t < 4; ++t)
        #pragma unroll
        for (int kc = 0; kc < 2; ++kc) {
            const int r0 = kc * 32 + g * 4;
            const int w  = t * 16 + col;
            f32x4 fa = *(f32x4*)&swout[w * CP + r0];
            f32x4 fb = *(f32x4*)&swout[w * CP + r0 + 16];
            bfrag[t][kc] = pack8(fa, fb);
        }

    const int cbase = wid * 16;

    for (int hr = 0; hr < RPB; ++hr) {
        const int h = h0 + hr;
        // ----- MFMA: s = (c_out * h_out) x w_out -----
        f32x4 acc0 = {0,0,0,0}, acc1 = {0,0,0,0}, acc2 = {0,0,0,0}, acc3 = {0,0,0,0};
        const int crow = cbase + col;     // A-operand row lives on lane&15
        #pragma unroll
        for (int kc = 0; kc < 2; ++kc) {
            const int r0 = kc * 32 + g * 4;
            f32x4 ca = *(f32x4*)&scout[crow * CP + r0];
            f32x4 cb = *(f32x4*)&scout[crow * CP + r0 + 16];
            f32x4 ha = *(f32x4*)&shout[hr * CP + r0];
            f32x4 hb = *(f32x4*)&shout[hr * CP + r0 + 16];
            s16x8 afrag = pack8(ca * ha, cb * hb);
            acc0 = __builtin_amdgcn_mfma_f32_16x16x32_bf16(afrag, bfrag[0][kc], acc0, 0, 0, 0);
            acc1 = __builtin_amdgcn_mfma_f32_16x16x32_bf16(afrag, bfrag[1][kc], acc1, 0, 0, 0);
            acc2 = __builtin_amdgcn_mfma_f32_16x16x32_bf16(afrag, bfrag[2][kc], acc2, 0, 0, 0);
            acc3 = __builtin_amdgcn_mfma_f32_16x16x32_bf16(afrag, bfrag[3][kc], acc3, 0, 0, 0);
        }
        // ----- write logits to LDS (D layout: row=4*(lane>>4)+reg, col=lane&15) -----
        {
            const int cr = cbase + g * 4;
            #pragma unroll
            for (int t = 0; t < 4; ++t) {
                const int w = t * 16 + col;
                if (w < W_) {
                    f32x4 a = (t == 0) ? acc0 : (t == 1) ? acc1 : (t == 2) ? acc2 : acc3;
                    sg[(cr + 0) * SGP + w] = a[0];
                    sg[(cr + 1) * SGP + w] = a[1];
                    sg[(cr + 2) * SGP + w] = a[2];
                    sg[(cr + 3) * SGP + w] = a[3];
                }
            }
        }
        __syncthreads();

        // ----- softmax over channels (lane = w, wave = 16-channel chunk) -----
        {
            float p[16];
            #pragma unroll
            for (int k = 0; k < 16; ++k) p[k] = sg[(cbase + k) * SGP + lane];
            float m16 = p[0];
            #pragma unroll
            for (int k = 1; k < 16; ++k) m16 = fmaxf(m16, p[k]);
            sredA[wid * 64 + lane] = m16;
            __syncthreads();
            float M = sredA[lane];
            #pragma unroll
            for (int t = 1; t < 16; ++t) M = fmaxf(M, sredA[t * 64 + lane]);
            float S = 0.f;
            #pragma unroll
            for (int k = 0; k < 16; ++k) { p[k] = __expf(p[k] - M); S += p[k]; }
            sredB[wid * 64 + lane] = S;
            __syncthreads();
            S = 0.f;
            #pragma unroll
            for (int t = 0; t < 16; ++t) S += sredB[t * 64 + lane];
            const float invS = 1.f / S;
            // overwrite logits with the final gate (each slot owned by this thread)
            #pragma unroll
            for (int k = 0; k < 16; ++k) sg[(cbase + k) * SGP + lane] = p[k] * invS;
        }

        // ----- conv3d (3x3x3, zero-pad), 2 chunks of 8 output channels -----
        const float* xb = x + (size_t)b * C_ * HW_;
        #pragma unroll
        for (int q = 0; q < 2; ++q) {
            float res[8];
            float xm[8];
            #pragma unroll
            for (int kk = 0; kk < 8; ++kk) res[kk] = 0.f;
            #pragma unroll
            for (int ci = 0; ci < 10; ++ci) {
                const int cc = cbase + q * 8 - 1 + ci;
                const bool cok = (cc >= 0) && (cc < C_);
                #pragma unroll
                for (int jh = 0; jh < 3; ++jh) {
                    const int hh = h - 1 + jh;
                    const bool hok = (hh >= 0) && (hh < H_);
                    float v = 0.f;
                    if (cok && hok && lane < W_) v = xb[(cc * H_ + hh) * W_ + lane];
                    float vl = __int_as_float(__builtin_amdgcn_mov_dpp(__float_as_int(v), 0x138, 0xf, 0xf, true)); // w-1
                    float vr = __int_as_float(__builtin_amdgcn_mov_dpp(__float_as_int(v), 0x130, 0xf, 0xf, true)); // w+1
                    vl = (lane == 0) ? 0.f : vl;
                    if (jh == 1 && ci >= 1 && ci <= 8) xm[ci - 1] = v;   // residual x
                    if (ci >= 2) { const int k = ci - 2;
                        res[k] += W3[(2*3+jh)*3+0]*vl + W3[(2*3+jh)*3+1]*v + W3[(2*3+jh)*3+2]*vr; }
                    if (ci >= 1 && ci <= 8) { const int k = ci - 1;
                        res[k] += W3[(1*3+jh)*3+0]*vl + W3[(1*3+jh)*3+1]*v + W3[(1*3+jh)*3+2]*vr; }
                    if (ci <= 7) { const int k = ci;
                        res[k] += W3[(0*3+jh)*3+0]*vl + W3[(0*3+jh)*3+1]*v + W3[(0*3+jh)*3+2]*vr; }
                }
            }
            // gated residual store for this chunk (gate re-read from LDS)
            if (lane < W_) {
                #pragma unroll
                for (int kk = 0; kk < 8; ++kk) {
                    const int k = q * 8 + kk;
                    const float gate = sg[(cbase + k) * SGP + lane];
                    const size_t idx = ((size_t)(b * C_ + cbase + k) * H_ + h) * W_ + lane;
                    out[idx] = res[kk] * gate + xm[kk];
                }
            }
        }
        __syncthreads();   // protect sg/sred reuse next row
    }
}

extern "C" void kernel_launch(void* const* d_in, const int* in_sizes, int n_in,
                              void* d_out, int out_size, void* d_ws, size_t ws_size,
                              hipStream_t stream) {
    const float* x  = (const float*)d_in[0];
    const float* Wc = (const float*)d_in[1];
    const float* ac = (const float*)d_in[2];
    const float* Ww = (const float*)d_in[3];
    const float* aw = (const float*)d_in[4];
    const float* Wh = (const float*)d_in[5];
    const float* ah = (const float*)d_in[6];
    const float* W3 = (const float*)d_in[7];
    float* out  = (float*)d_out;
    float* gapc = (float*)d_ws;                 // B*C
    float* gwp  = gapc + B_ * C_;               // B*W (raw sums)
    float* ghp  = gwp + B_ * W_;                // B*H (raw sums)

    hipMemsetAsync(gwp, 0, (size_t)(B_ * W_ + B_ * H_) * sizeof(float), stream);
    k_reduce<<<dim3(B_ * C_), dim3(256), 0, stream>>>(x, gapc, gwp, ghp);
    k_main<<<dim3(B_, H_ / RPB), dim3(1024), 0, stream>>>(
        x, Wc, ac, Ww, aw, Wh, ah, W3, gapc, gwp, ghp, out);
}

// Round 4
// 283.712 us; speedup vs baseline: 2.5456x; 1.3770x over previous
//
#include <hip/hip_runtime.h>

typedef float f32x4 __attribute__((ext_vector_type(4)));
typedef short s16x8 __attribute__((ext_vector_type(8)));

#define B_ 32
#define C_ 256
#define H_ 56
#define W_ 56
#define R_ 64
#define HW_ (H_*W_)     // 3136
#define CH_ 14336       // C_*H_ == C_*W_
#define RPB 2           // h-rows per block in main kernel
#define CP 68           // padded r-stride (bank-conflict-free f32x4 reads)
#define SGP 58          // padded w-stride for logit tile

// ---------- helpers ----------
__device__ __forceinline__ unsigned short f2bf(float f) {
    unsigned u = __float_as_uint(f);
    u += 0x7fffu + ((u >> 16) & 1u);     // round-to-nearest-even
    return (unsigned short)(u >> 16);
}

__device__ __forceinline__ s16x8 pack8(f32x4 a, f32x4 b) {
    s16x8 r;
    r[0] = (short)f2bf(a[0]); r[1] = (short)f2bf(a[1]);
    r[2] = (short)f2bf(a[2]); r[3] = (short)f2bf(a[3]);
    r[4] = (short)f2bf(b[0]); r[5] = (short)f2bf(b[1]);
    r[6] = (short)f2bf(b[2]); r[7] = (short)f2bf(b[3]);
    return r;
}

// ---------- K1: GAP reductions ----------
__global__ __launch_bounds__(256) void k_reduce(const float* __restrict__ x,
                                                float* __restrict__ gapc,
                                                float* __restrict__ gw,
                                                float* __restrict__ gh) {
    const int b = blockIdx.x >> 8;
    const int c = blockIdx.x & 255;
    const float* px = x + (size_t)(b * C_ + c) * HW_;
    __shared__ float sp[HW_];
    __shared__ float spart[4];
    const int tid = threadIdx.x;
    float tot = 0.f;
    for (int j = tid; j < HW_ / 4; j += 256) {
        f32x4 v = *(const f32x4*)(px + j * 4);
        *(f32x4*)&sp[j * 4] = v;
        tot += v[0] + v[1] + v[2] + v[3];
    }
    for (int d = 32; d > 0; d >>= 1) tot += __shfl_xor(tot, d, 64);
    const int lane = tid & 63, wid = tid >> 6;
    if (lane == 0) spart[wid] = tot;
    __syncthreads();
    if (tid == 0)
        gapc[b * C_ + c] = (spart[0] + spart[1] + spart[2] + spart[3]) * (1.f / HW_);
    if (tid < W_) {
        float s = 0.f;
        for (int h = 0; h < H_; ++h) s += sp[h * W_ + tid];
        atomicAdd(&gw[b * W_ + tid], s);
    } else if (tid >= 64 && tid < 64 + H_) {
        const int h = tid - 64;
        float s = 0.f;
        for (int w = 0; w < W_; ++w) s += sp[h * W_ + w];
        atomicAdd(&gh[b * H_ + h], s);
    }
}

// ---------- K3: fused CP-reconstruct + softmax + conv3d gate ----------
// Register-lifetime-disciplined: gate lives in LDS; conv in 4 chunks of 4
// channels with unroll-1 chunk loop (scheduling fence -> <=18 loads in flight);
// bfrag built inside the hr loop so it is live only during the MFMA phase.
__global__ __launch_bounds__(1024)
__attribute__((amdgpu_waves_per_eu(4, 4)))
void k_main(
    const float* __restrict__ x,
    const float* __restrict__ Wc, const float* __restrict__ acp,
    const float* __restrict__ Ww, const float* __restrict__ awp,
    const float* __restrict__ Wh, const float* __restrict__ ahp,
    const float* __restrict__ W3,
    const float* __restrict__ gapc, const float* __restrict__ gw,
    const float* __restrict__ gh,
    float* __restrict__ out)
{
    __shared__ float scout[C_ * CP];          // c_out[b][c][r]          69632 B
    __shared__ float swout[64 * CP];          // w_out[b][w][r]          17408 B
    __shared__ float shout[RPB * CP];         // h_out[b][h0+hr][r]        544 B
    __shared__ float sg[C_ * SGP + 16];       // logits -> gates         59456 B
    __shared__ float sredA[16 * 64];          //                          4096 B
    __shared__ float sredB[16 * 64];          //                          4096 B

    const int b   = blockIdx.x;
    const int h0  = blockIdx.y * RPB;
    const int tid = threadIdx.x;
    const int lane = tid & 63;
    const int wid  = tid >> 6;
    const int g    = lane >> 4;
    const int col  = lane & 15;
    const float ac = acp[0], aw = awp[0], ah = ahp[0];

    // ----- staging: build factor matrices straight from the GAP results -----
    const float* gc = gapc + b * C_;
    for (int idx = tid; idx < C_ * R_; idx += 1024) {
        const int c = idx >> 6, r = idx & 63;
        const float gm = (c >= 1)      ? gc[c - 1] : 0.f;
        const float g0 = gc[c];
        const float gp = (c < C_ - 1)  ? gc[c + 1] : 0.f;
        float v = Wc[r * 3 + 0] * gm + Wc[r * 3 + 1] * g0 + Wc[r * 3 + 2] * gp;
        scout[c * CP + r] = (v >= 0.f) ? v : ac * v;
    }
    const float* gwb = gw + b * W_;
    for (int idx = tid; idx < 64 * R_; idx += 1024) {
        const int w = idx >> 6, r = idx & 63;
        float v = 0.f;
        if (w < W_) {
            const float gm = (w >= 1)     ? gwb[w - 1] * (1.f / CH_) : 0.f;
            const float g0 = gwb[w] * (1.f / CH_);
            const float gp = (w < W_ - 1) ? gwb[w + 1] * (1.f / CH_) : 0.f;
            v = Ww[r * 3 + 0] * gm + Ww[r * 3 + 1] * g0 + Ww[r * 3 + 2] * gp;
            v = (v >= 0.f) ? v : aw * v;
        }
        swout[w * CP + r] = v;
    }
    const float* ghb = gh + b * H_;
    if (tid < RPB * R_) {
        const int hr = tid >> 6, r = tid & 63;
        const int h = h0 + hr;
        const float gm = (h >= 1)     ? ghb[h - 1] * (1.f / CH_) : 0.f;
        const float g0 = ghb[h] * (1.f / CH_);
        const float gp = (h < H_ - 1) ? ghb[h + 1] * (1.f / CH_) : 0.f;
        float v = Wh[r * 3 + 0] * gm + Wh[r * 3 + 1] * g0 + Wh[r * 3 + 2] * gp;
        shout[hr * CP + r] = (v >= 0.f) ? v : ah * v;
    }
    __syncthreads();

    const int cbase = wid * 16;

    for (int hr = 0; hr < RPB; ++hr) {
        const int h = h0 + hr;
        // ----- MFMA: s = (c_out * h_out) x w_out -----
        f32x4 acc0 = {0,0,0,0}, acc1 = {0,0,0,0}, acc2 = {0,0,0,0}, acc3 = {0,0,0,0};
        const int crow = cbase + col;     // A-operand row lives on lane&15
        #pragma unroll
        for (int kc = 0; kc < 2; ++kc) {
            const int r0 = kc * 32 + g * 4;
            f32x4 ca = *(f32x4*)&scout[crow * CP + r0];
            f32x4 cb = *(f32x4*)&scout[crow * CP + r0 + 16];
            f32x4 ha = *(f32x4*)&shout[hr * CP + r0];
            f32x4 hb = *(f32x4*)&shout[hr * CP + r0 + 16];
            s16x8 afrag = pack8(ca * ha, cb * hb);
            // B fragments built on the fly (live only here)
            {
                f32x4 fa = *(f32x4*)&swout[(0 * 16 + col) * CP + r0];
                f32x4 fb = *(f32x4*)&swout[(0 * 16 + col) * CP + r0 + 16];
                acc0 = __builtin_amdgcn_mfma_f32_16x16x32_bf16(afrag, pack8(fa, fb), acc0, 0, 0, 0);
            }
            {
                f32x4 fa = *(f32x4*)&swout[(1 * 16 + col) * CP + r0];
                f32x4 fb = *(f32x4*)&swout[(1 * 16 + col) * CP + r0 + 16];
                acc1 = __builtin_amdgcn_mfma_f32_16x16x32_bf16(afrag, pack8(fa, fb), acc1, 0, 0, 0);
            }
            {
                f32x4 fa = *(f32x4*)&swout[(2 * 16 + col) * CP + r0];
                f32x4 fb = *(f32x4*)&swout[(2 * 16 + col) * CP + r0 + 16];
                acc2 = __builtin_amdgcn_mfma_f32_16x16x32_bf16(afrag, pack8(fa, fb), acc2, 0, 0, 0);
            }
            {
                f32x4 fa = *(f32x4*)&swout[(3 * 16 + col) * CP + r0];
                f32x4 fb = *(f32x4*)&swout[(3 * 16 + col) * CP + r0 + 16];
                acc3 = __builtin_amdgcn_mfma_f32_16x16x32_bf16(afrag, pack8(fa, fb), acc3, 0, 0, 0);
            }
        }
        // ----- write logits to LDS (D layout: row=4*(lane>>4)+reg, col=lane&15) -----
        {
            const int cr = cbase + g * 4;
            #pragma unroll
            for (int t = 0; t < 4; ++t) {
                const int w = t * 16 + col;
                if (w < W_) {
                    f32x4 a = (t == 0) ? acc0 : (t == 1) ? acc1 : (t == 2) ? acc2 : acc3;
                    sg[(cr + 0) * SGP + w] = a[0];
                    sg[(cr + 1) * SGP + w] = a[1];
                    sg[(cr + 2) * SGP + w] = a[2];
                    sg[(cr + 3) * SGP + w] = a[3];
                }
            }
        }
        __syncthreads();

        // ----- softmax over channels (lane = w, wave = 16-channel chunk) -----
        {
            float p[16];
            #pragma unroll
            for (int k = 0; k < 16; ++k) p[k] = sg[(cbase + k) * SGP + lane];
            float m16 = p[0];
            #pragma unroll
            for (int k = 1; k < 16; ++k) m16 = fmaxf(m16, p[k]);
            sredA[wid * 64 + lane] = m16;
            __syncthreads();
            float M = sredA[lane];
            #pragma unroll
            for (int t = 1; t < 16; ++t) M = fmaxf(M, sredA[t * 64 + lane]);
            float S = 0.f;
            #pragma unroll
            for (int k = 0; k < 16; ++k) { p[k] = __expf(p[k] - M); S += p[k]; }
            sredB[wid * 64 + lane] = S;
            __syncthreads();
            S = 0.f;
            #pragma unroll
            for (int t = 0; t < 16; ++t) S += sredB[t * 64 + lane];
            const float invS = 1.f / S;
            // overwrite logits with the final gate (each slot owned by this thread)
            #pragma unroll
            for (int k = 0; k < 16; ++k) sg[(cbase + k) * SGP + lane] = p[k] * invS;
        }

        // ----- conv3d (3x3x3, zero-pad), 4 chunks of 4 output channels -----
        // unroll 1: the loop back-edge stops the scheduler from hoisting all
        // chunks' global loads into one giant live set (the round-1/2 spill).
        const float* xb = x + (size_t)b * C_ * HW_;
        #pragma unroll 1
        for (int q = 0; q < 4; ++q) {
            float res[4];
            float xm[4];
            #pragma unroll
            for (int kk = 0; kk < 4; ++kk) res[kk] = 0.f;
            #pragma unroll
            for (int ci = 0; ci < 6; ++ci) {
                const int cc = cbase + q * 4 - 1 + ci;
                const bool cok = (cc >= 0) && (cc < C_);
                #pragma unroll
                for (int jh = 0; jh < 3; ++jh) {
                    const int hh = h - 1 + jh;
                    const bool hok = (hh >= 0) && (hh < H_);
                    float v = 0.f;
                    if (cok && hok && lane < W_) v = xb[(cc * H_ + hh) * W_ + lane];
                    float vl = __int_as_float(__builtin_amdgcn_mov_dpp(__float_as_int(v), 0x138, 0xf, 0xf, true)); // w-1
                    float vr = __int_as_float(__builtin_amdgcn_mov_dpp(__float_as_int(v), 0x130, 0xf, 0xf, true)); // w+1
                    vl = (lane == 0) ? 0.f : vl;
                    if (jh == 1 && ci >= 1 && ci <= 4) xm[ci - 1] = v;   // residual x
                    if (ci >= 2) { const int k = ci - 2;
                        res[k] += W3[(2*3+jh)*3+0]*vl + W3[(2*3+jh)*3+1]*v + W3[(2*3+jh)*3+2]*vr; }
                    if (ci >= 1 && ci <= 4) { const int k = ci - 1;
                        res[k] += W3[(1*3+jh)*3+0]*vl + W3[(1*3+jh)*3+1]*v + W3[(1*3+jh)*3+2]*vr; }
                    if (ci <= 3) { const int k = ci;
                        res[k] += W3[(0*3+jh)*3+0]*vl + W3[(0*3+jh)*3+1]*v + W3[(0*3+jh)*3+2]*vr; }
                }
            }
            // gated residual store for this chunk (gate re-read from LDS)
            if (lane < W_) {
                #pragma unroll
                for (int kk = 0; kk < 4; ++kk) {
                    const int k = q * 4 + kk;
                    const float gate = sg[(cbase + k) * SGP + lane];
                    const size_t idx = ((size_t)(b * C_ + cbase + k) * H_ + h) * W_ + lane;
                    out[idx] = res[kk] * gate + xm[kk];
                }
            }
        }
        __syncthreads();   // protect sg/sred reuse next row
    }
}

extern "C" void kernel_launch(void* const* d_in, const int* in_sizes, int n_in,
                              void* d_out, int out_size, void* d_ws, size_t ws_size,
                              hipStream_t stream) {
    const float* x  = (const float*)d_in[0];
    const float* Wc = (const float*)d_in[1];
    const float* ac = (const float*)d_in[2];
    const float* Ww = (const float*)d_in[3];
    const float* aw = (const float*)d_in[4];
    const float* Wh = (const float*)d_in[5];
    const float* ah = (const float*)d_in[6];
    const float* W3 = (const float*)d_in[7];
    float* out  = (float*)d_out;
    float* gapc = (float*)d_ws;                 // B*C
    float* gwp  = gapc + B_ * C_;               // B*W (raw sums)
    float* ghp  = gwp + B_ * W_;                // B*H (raw sums)

    hipMemsetAsync(gwp, 0, (size_t)(B_ * W_ + B_ * H_) * sizeof(float), stream);
    k_reduce<<<dim3(B_ * C_), dim3(256), 0, stream>>>(x, gapc, gwp, ghp);
    k_main<<<dim3(B_, H_ / RPB), dim3(1024), 0, stream>>>(
        x, Wc, ac, Ww, aw, Wh, ah, W3, gapc, gwp, ghp, out);
}

// Round 6
// 210.737 us; speedup vs baseline: 3.4271x; 1.3463x over previous
//
#include <hip/hip_runtime.h>

typedef float f32x4 __attribute__((ext_vector_type(4)));
typedef short s16x8 __attribute__((ext_vector_type(8)));
typedef unsigned short ush4 __attribute__((ext_vector_type(4)));

#define B_ 32
#define C_ 256
#define H_ 56
#define W_ 56
#define R_ 64
#define HW_ (H_*W_)     // 3136
#define CH_ 14336       // C_*H_ == C_*W_
#define RPB 2           // h-rows per block in main kernel
#define CPH 68          // ushort stride for scout/swout (8B-aligned b64 frag loads)
#define CP 68           // float stride for shout
#define SGP 58          // ushort stride for sg

// ---------- helpers ----------
__device__ __forceinline__ unsigned short f2bf(float f) {
    unsigned u = __float_as_uint(f);
    u += 0x7fffu + ((u >> 16) & 1u);     // round-to-nearest-even
    return (unsigned short)(u >> 16);
}
__device__ __forceinline__ float bf2f(unsigned short u) {
    return __uint_as_float((unsigned)u << 16);
}
__device__ __forceinline__ f32x4 bf2f4(ush4 u) {
    f32x4 r; r[0] = bf2f(u[0]); r[1] = bf2f(u[1]); r[2] = bf2f(u[2]); r[3] = bf2f(u[3]);
    return r;
}
__device__ __forceinline__ s16x8 pack8(f32x4 a, f32x4 b) {
    s16x8 r;
    r[0] = (short)f2bf(a[0]); r[1] = (short)f2bf(a[1]);
    r[2] = (short)f2bf(a[2]); r[3] = (short)f2bf(a[3]);
    r[4] = (short)f2bf(b[0]); r[5] = (short)f2bf(b[1]);
    r[6] = (short)f2bf(b[2]); r[7] = (short)f2bf(b[3]);
    return r;
}
__device__ __forceinline__ s16x8 cat8(ush4 a, ush4 b) {
    s16x8 r;
    r[0] = (short)a[0]; r[1] = (short)a[1]; r[2] = (short)a[2]; r[3] = (short)a[3];
    r[4] = (short)b[0]; r[5] = (short)b[1]; r[6] = (short)b[2]; r[7] = (short)b[3];
    return r;
}

// ---------- K1: GAP reductions ----------
__global__ __launch_bounds__(256) void k_reduce(const float* __restrict__ x,
                                                float* __restrict__ gapc,
                                                float* __restrict__ gw,
                                                float* __restrict__ gh) {
    const int b = blockIdx.x >> 8;
    const int c = blockIdx.x & 255;
    const float* px = x + (size_t)(b * C_ + c) * HW_;
    __shared__ float sp[HW_];
    __shared__ float spart[4];
    const int tid = threadIdx.x;
    float tot = 0.f;
    for (int j = tid; j < HW_ / 4; j += 256) {
        f32x4 v = *(const f32x4*)(px + j * 4);
        *(f32x4*)&sp[j * 4] = v;
        tot += v[0] + v[1] + v[2] + v[3];
    }
    for (int d = 32; d > 0; d >>= 1) tot += __shfl_xor(tot, d, 64);
    const int lane = tid & 63, wid = tid >> 6;
    if (lane == 0) spart[wid] = tot;
    __syncthreads();
    if (tid == 0)
        gapc[b * C_ + c] = (spart[0] + spart[1] + spart[2] + spart[3]) * (1.f / HW_);
    if (tid < W_) {
        float s = 0.f;
        for (int h = 0; h < H_; ++h) s += sp[h * W_ + tid];
        atomicAdd(&gw[b * W_ + tid], s);
    } else if (tid >= 64 && tid < 64 + H_) {
        const int h = tid - 64;
        float s = 0.f;
        for (int w = 0; w < W_; ++w) s += sp[h * W_ + w];
        atomicAdd(&gh[b * H_ + h], s);
    }
}

// ---------- K3: fused CP-reconstruct + softmax + conv3d gate ----------
// LDS diet (~78 KB, bf16 factor/logit tiles) -> 2 blocks/CU for phase overlap.
// Softmax phase: lanes >= W_ clamp their reads (never touch unwritten LDS) and
// never write (round-5 NaN bug: lane 58..63 writes aliased the next row).
__global__ __launch_bounds__(1024)
__attribute__((amdgpu_waves_per_eu(8)))
void k_main(
    const float* __restrict__ x,
    const float* __restrict__ Wc, const float* __restrict__ acp,
    const float* __restrict__ Ww, const float* __restrict__ awp,
    const float* __restrict__ Wh, const float* __restrict__ ahp,
    const float* __restrict__ W3,
    const float* __restrict__ gapc, const float* __restrict__ gw,
    const float* __restrict__ gh,
    float* __restrict__ out)
{
    __shared__ unsigned short scout[C_ * CPH];   // c_out bf16          34816 B
    __shared__ unsigned short swout[64 * CPH];   // w_out bf16 (=B frag) 8704 B
    __shared__ float          shout[RPB * CP];   // h_out f32             544 B
    __shared__ unsigned short sg[C_ * SGP + 32]; // logits->gates bf16  29760 B
    __shared__ float          sred[16 * 64];     // cross-wave reduce    4096 B

    const int b   = blockIdx.x;
    const int h0  = blockIdx.y * RPB;
    const int tid = threadIdx.x;
    const int lane = tid & 63;
    const int wid  = tid >> 6;
    const int g    = lane >> 4;
    const int col  = lane & 15;
    const int lw   = (lane < W_) ? lane : (W_ - 1);   // clamped column for softmax reads
    const float ac = acp[0], aw = awp[0], ah = ahp[0];

    // ----- staging: factor matrices straight from the GAP results (bf16) -----
    const float* gc = gapc + b * C_;
    for (int idx = tid; idx < C_ * R_; idx += 1024) {
        const int c = idx >> 6, r = idx & 63;
        const float gm = (c >= 1)      ? gc[c - 1] : 0.f;
        const float g0 = gc[c];
        const float gp = (c < C_ - 1)  ? gc[c + 1] : 0.f;
        float v = Wc[r * 3 + 0] * gm + Wc[r * 3 + 1] * g0 + Wc[r * 3 + 2] * gp;
        scout[c * CPH + r] = f2bf((v >= 0.f) ? v : ac * v);
    }
    const float* gwb = gw + b * W_;
    for (int idx = tid; idx < 64 * R_; idx += 1024) {
        const int w = idx >> 6, r = idx & 63;
        float v = 0.f;
        if (w < W_) {
            const float gm = (w >= 1)     ? gwb[w - 1] * (1.f / CH_) : 0.f;
            const float g0 = gwb[w] * (1.f / CH_);
            const float gp = (w < W_ - 1) ? gwb[w + 1] * (1.f / CH_) : 0.f;
            v = Ww[r * 3 + 0] * gm + Ww[r * 3 + 1] * g0 + Ww[r * 3 + 2] * gp;
            v = (v >= 0.f) ? v : aw * v;
        }
        swout[w * CPH + r] = f2bf(v);
    }
    const float* ghb = gh + b * H_;
    if (tid < RPB * R_) {
        const int hr = tid >> 6, r = tid & 63;
        const int h = h0 + hr;
        const float gm = (h >= 1)     ? ghb[h - 1] * (1.f / CH_) : 0.f;
        const float g0 = ghb[h] * (1.f / CH_);
        const float gp = (h < H_ - 1) ? ghb[h + 1] * (1.f / CH_) : 0.f;
        float v = Wh[r * 3 + 0] * gm + Wh[r * 3 + 1] * g0 + Wh[r * 3 + 2] * gp;
        shout[hr * CP + r] = (v >= 0.f) ? v : ah * v;
    }
    __syncthreads();

    const int cbase = wid * 16;

    for (int hr = 0; hr < RPB; ++hr) {
        const int h = h0 + hr;
        // ----- MFMA: s = (c_out * h_out) x w_out -----
        f32x4 acc0 = {0,0,0,0}, acc1 = {0,0,0,0}, acc2 = {0,0,0,0}, acc3 = {0,0,0,0};
        const int crow = cbase + col;     // A-operand row on lane&15
        #pragma unroll
        for (int kc = 0; kc < 2; ++kc) {
            const int r0 = kc * 32 + g * 4;
            f32x4 ca = bf2f4(*(ush4*)&scout[crow * CPH + r0]);
            f32x4 cb = bf2f4(*(ush4*)&scout[crow * CPH + r0 + 16]);
            f32x4 ha = *(f32x4*)&shout[hr * CP + r0];
            f32x4 hb = *(f32x4*)&shout[hr * CP + r0 + 16];
            s16x8 afrag = pack8(ca * ha, cb * hb);
            acc0 = __builtin_amdgcn_mfma_f32_16x16x32_bf16(afrag,
                    cat8(*(ush4*)&swout[(0*16+col)*CPH + r0], *(ush4*)&swout[(0*16+col)*CPH + r0 + 16]),
                    acc0, 0, 0, 0);
            acc1 = __builtin_amdgcn_mfma_f32_16x16x32_bf16(afrag,
                    cat8(*(ush4*)&swout[(1*16+col)*CPH + r0], *(ush4*)&swout[(1*16+col)*CPH + r0 + 16]),
                    acc1, 0, 0, 0);
            acc2 = __builtin_amdgcn_mfma_f32_16x16x32_bf16(afrag,
                    cat8(*(ush4*)&swout[(2*16+col)*CPH + r0], *(ush4*)&swout[(2*16+col)*CPH + r0 + 16]),
                    acc2, 0, 0, 0);
            acc3 = __builtin_amdgcn_mfma_f32_16x16x32_bf16(afrag,
                    cat8(*(ush4*)&swout[(3*16+col)*CPH + r0], *(ush4*)&swout[(3*16+col)*CPH + r0 + 16]),
                    acc3, 0, 0, 0);
        }
        // ----- logits to LDS (bf16; D layout: row=4*(lane>>4)+reg, col=lane&15) -----
        {
            const int cr = cbase + g * 4;
            #pragma unroll
            for (int t = 0; t < 4; ++t) {
                const int w = t * 16 + col;
                if (w < W_) {
                    f32x4 a = (t == 0) ? acc0 : (t == 1) ? acc1 : (t == 2) ? acc2 : acc3;
                    sg[(cr + 0) * SGP + w] = f2bf(a[0]);
                    sg[(cr + 1) * SGP + w] = f2bf(a[1]);
                    sg[(cr + 2) * SGP + w] = f2bf(a[2]);
                    sg[(cr + 3) * SGP + w] = f2bf(a[3]);
                }
            }
        }
        __syncthreads();

        // ----- softmax over channels (lane = w [clamped], wave = 16-ch chunk) -----
        {
            float p[16];
            #pragma unroll
            for (int k = 0; k < 16; ++k) p[k] = bf2f(sg[(cbase + k) * SGP + lw]);
            float m16 = p[0];
            #pragma unroll
            for (int k = 1; k < 16; ++k) m16 = fmaxf(m16, p[k]);
            sred[wid * 64 + lane] = m16;
            __syncthreads();
            float M = sred[lane];
            #pragma unroll
            for (int t = 1; t < 16; ++t) M = fmaxf(M, sred[t * 64 + lane]);
            // lanes >= W_ have a duplicate (clamped) column; their M/S stay in-lane
            float S = 0.f;
            #pragma unroll
            for (int k = 0; k < 16; ++k) { p[k] = __expf(p[k] - M); S += p[k]; }
            __syncthreads();                  // all reads of sred done before reuse
            sred[wid * 64 + lane] = S;
            __syncthreads();
            S = 0.f;
            #pragma unroll
            for (int t = 0; t < 16; ++t) S += sred[t * 64 + lane];
            const float invS = 1.f / S;
            // overwrite logits with the final gate; ONLY owning lanes write
            if (lane < W_) {
                #pragma unroll
                for (int k = 0; k < 16; ++k) sg[(cbase + k) * SGP + lane] = f2bf(p[k] * invS);
            }
        }

        // ----- conv3d (3x3x3, zero-pad), 4 chunks of 4 output channels -----
        // unroll 1: back-edge fences scheduler -> bounded live loads (no spill)
        const float* xb = x + (size_t)b * C_ * HW_;
        #pragma unroll 1
        for (int q = 0; q < 4; ++q) {
            float res[4];
            float xm[4];
            #pragma unroll
            for (int kk = 0; kk < 4; ++kk) res[kk] = 0.f;
            #pragma unroll
            for (int ci = 0; ci < 6; ++ci) {
                const int cc = cbase + q * 4 - 1 + ci;
                const bool cok = (cc >= 0) && (cc < C_);
                #pragma unroll
                for (int jh = 0; jh < 3; ++jh) {
                    const int hh = h - 1 + jh;
                    const bool hok = (hh >= 0) && (hh < H_);
                    float v = 0.f;
                    if (cok && hok && lane < W_) v = xb[(cc * H_ + hh) * W_ + lane];
                    float vl = __int_as_float(__builtin_amdgcn_mov_dpp(__float_as_int(v), 0x138, 0xf, 0xf, true)); // w-1
                    float vr = __int_as_float(__builtin_amdgcn_mov_dpp(__float_as_int(v), 0x130, 0xf, 0xf, true)); // w+1
                    vl = (lane == 0) ? 0.f : vl;
                    if (jh == 1 && ci >= 1 && ci <= 4) xm[ci - 1] = v;   // residual x
                    if (ci >= 2) { const int k = ci - 2;
                        res[k] += W3[(2*3+jh)*3+0]*vl + W3[(2*3+jh)*3+1]*v + W3[(2*3+jh)*3+2]*vr; }
                    if (ci >= 1 && ci <= 4) { const int k = ci - 1;
                        res[k] += W3[(1*3+jh)*3+0]*vl + W3[(1*3+jh)*3+1]*v + W3[(1*3+jh)*3+2]*vr; }
                    if (ci <= 3) { const int k = ci;
                        res[k] += W3[(0*3+jh)*3+0]*vl + W3[(0*3+jh)*3+1]*v + W3[(0*3+jh)*3+2]*vr; }
                }
            }
            // gated residual store for this chunk (gate re-read from LDS)
            if (lane < W_) {
                #pragma unroll
                for (int kk = 0; kk < 4; ++kk) {
                    const int k = q * 4 + kk;
                    const float gate = bf2f(sg[(cbase + k) * SGP + lane]);
                    const size_t idx = ((size_t)(b * C_ + cbase + k) * H_ + h) * W_ + lane;
                    out[idx] = res[kk] * gate + xm[kk];
                }
            }
        }
        __syncthreads();   // protect sg/sred reuse next row
    }
}

extern "C" void kernel_launch(void* const* d_in, const int* in_sizes, int n_in,
                              void* d_out, int out_size, void* d_ws, size_t ws_size,
                              hipStream_t stream) {
    const float* x  = (const float*)d_in[0];
    const float* Wc = (const float*)d_in[1];
    const float* ac = (const float*)d_in[2];
    const float* Ww = (const float*)d_in[3];
    const float* aw = (const float*)d_in[4];
    const float* Wh = (const float*)d_in[5];
    const float* ah = (const float*)d_in[6];
    const float* W3 = (const float*)d_in[7];
    float* out  = (float*)d_out;
    float* gapc = (float*)d_ws;                 // B*C
    float* gwp  = gapc + B_ * C_;               // B*W (raw sums)
    float* ghp  = gwp + B_ * W_;                // B*H (raw sums)

    hipMemsetAsync(gwp, 0, (size_t)(B_ * W_ + B_ * H_) * sizeof(float), stream);
    k_reduce<<<dim3(B_ * C_), dim3(256), 0, stream>>>(x, gapc, gwp, ghp);
    k_main<<<dim3(B_, H_ / RPB), dim3(1024), 0, stream>>>(
        x, Wc, ac, Ww, aw, Wh, ah, W3, gapc, gwp, ghp, out);
}